// Round 4
// baseline (1159.062 us; speedup 1.0000x reference)
//
#include <hip/hip_runtime.h>
#include <hip/hip_bf16.h>

#define N_SPOKES 524288
#define DIM      128
#define DIM2     256
#define NB       128
#define NH       64
#define BH       8192   // NB*NH

// d_out layout (all float32): [0,1048576) hub_features [8192][128]
//                             [1048576, +2097152) spokes_idx row
//                             [3145728, +2097152) hub ids row
#define OUT_HF   0
#define OUT_E0   1048576
#define OUT_E1   3145728

typedef __attribute__((ext_vector_type(8))) short  short8;
typedef __attribute__((ext_vector_type(4))) float  float4v;
typedef __attribute__((ext_vector_type(4))) unsigned short ushort4v;

__device__ inline unsigned short f2bf(float f) {
    __hip_bfloat16 h = __float2bfloat16(f);
    return *reinterpret_cast<unsigned short*>(&h);
}

// tanh-approx GELU via sigmoid identity: 0.5x(1+tanh(t)) = x*sigmoid(2t)
__device__ inline float gelu_f(float v) {
    float s = v * (1.0f + 0.044715f * v * v);            // v + 0.044715 v^3
    float e = __builtin_exp2f(-2.302118131f * s);        // exp(-1.5957691*s)
    return v / (1.0f + e);
}

// ---------- prep: W1 [128][256] f32 -> W1^T bf16 [n=256][k=128] ----------
__global__ void prep_w1t(const float* __restrict__ W1, unsigned short* __restrict__ w1t) {
    int idx = blockIdx.x * 256 + threadIdx.x;   // 32768 total
    if (idx < DIM * DIM2) {
        int n = idx >> 7;          // output col
        int k = idx & 127;
        w1t[idx] = f2bf(W1[k * DIM2 + n]);
    }
}

// ---------- graph start offsets from sorted batch_idx ----------
__global__ void goff_kernel(const int* __restrict__ batchidx, int* __restrict__ goff) {
    int i = blockIdx.x * 256 + threadIdx.x;
    if (i >= N_SPOKES) return;
    int bi = batchidx[i];
    int bp = (i == 0) ? -1 : batchidx[i - 1];
    for (int g = bp + 1; g <= bi; ++g) goff[g] = i;
    if (i == N_SPOKES - 1)
        for (int g = bi + 1; g <= NB; ++g) goff[g] = N_SPOKES;
}

// ---------- counts per hub ----------
__global__ void count_kernel(const int* __restrict__ hubidx, const int* __restrict__ batchidx,
                             int* __restrict__ cnt) {
    int i = blockIdx.x * 256 + threadIdx.x;
    if (i < N_SPOKES) {
        atomicAdd(&cnt[batchidx[i] * NH + hubidx[i]], 1);
    }
}

// ---------- fused: U = gelu(x@W1+b1) accumulated per-hub in LDS, one flush ----------
// 256 blocks = 128 graphs x 2 chunks. Block tile M=128, N=256, K=128 one-shot.
// LDS: sA 34.8K + accS 66.6K + sHub 0.5K ~= 100K -> 1 block/CU (intentional).
// Register prefetch (16 x float4/thread) hides the HBM read behind MFMA+epilogue.
__launch_bounds__(256, 1)
__global__ void ffn_fused(const float* __restrict__ x,
                          const int* __restrict__ hubidx,
                          const int* __restrict__ goff,
                          const unsigned short* __restrict__ w1t,
                          const float* __restrict__ b1,
                          float* __restrict__ outbuf,   // partial[2][BH][256] or hubsum[BH][256]
                          int atomic_mode) {
    __shared__ unsigned short sA[128 * 136];   // bf16 A tile, row stride 136
    __shared__ float accS[NH * 260];           // hub accumulator, stride 260
    __shared__ int sHub[128];

    const int tid  = threadIdx.x;
    const int lane = tid & 63;
    const int w    = tid >> 6;
    const int c_lo = lane & 15;
    const int c_hi = lane >> 4;
    const int g      = blockIdx.x >> 1;
    const int cchunk = blockIdx.x & 1;

    const int s = goff[g], e = goff[g + 1];
    const int len = e - s;
    const int cs  = (len + 1) >> 1;
    const int ms  = s + cchunk * cs;
    int me = ms + cs; if (me > e) me = e;
    const int n  = me - ms;
    const int nt = (n + 127) >> 7;

    for (int i = tid; i < NH * 260; i += 256) accS[i] = 0.f;

    // B fragments + bias, wave-private columns (L1-resident)
    short8 bfr[4][4];
    #pragma unroll
    for (int n4 = 0; n4 < 4; ++n4)
        #pragma unroll
        for (int k = 0; k < 4; ++k) {
            int col = w * 64 + n4 * 16 + c_lo;
            bfr[n4][k] = *(const short8*)(w1t + col * DIM + k * 32 + c_hi * 8);
        }
    float bcol[4];
    #pragma unroll
    for (int n4 = 0; n4 < 4; ++n4) bcol[n4] = b1[w * 64 + n4 * 16 + c_lo];

    const float4v* x4 = (const float4v*)x;

    float4v pf[16];
    if (nt > 0) {
        #pragma unroll
        for (int it = 0; it < 16; ++it) {
            int f = it * 256 + tid;
            int r = f >> 5;                         // tile-local row, t=0
            int rr = r < n ? r : n - 1;             // clamp (dup last row; masked later)
            pf[it] = x4[(size_t)(ms + rr) * 32 + (f & 31)];
        }
    }

    for (int t = 0; t < nt; ++t) {
        // stage prefetched tile -> sA (f32->bf16)
        #pragma unroll
        for (int it = 0; it < 16; ++it) {
            int f = it * 256 + tid;
            int row = f >> 5, c4 = f & 31;
            float4v v = pf[it];
            ushort4v u = { f2bf(v.x), f2bf(v.y), f2bf(v.z), f2bf(v.w) };
            *(ushort4v*)&sA[row * 136 + c4 * 4] = u;
        }
        if (tid < 128) {
            int r = t * 128 + tid;
            sHub[tid] = (r < n) ? hubidx[ms + r] : 0;
        }
        __syncthreads();

        // issue next tile's loads; they fly during MFMA+epilogue
        if (t + 1 < nt) {
            #pragma unroll
            for (int it = 0; it < 16; ++it) {
                int f = it * 256 + tid;
                int r = (t + 1) * 128 + (f >> 5);
                int rr = r < n ? r : n - 1;
                pf[it] = x4[(size_t)(ms + rr) * 32 + (f & 31)];
            }
        }

        float4v acc[8][4];
        #pragma unroll
        for (int m = 0; m < 8; ++m)
            #pragma unroll
            for (int n4 = 0; n4 < 4; ++n4) acc[m][n4] = (float4v){0.f, 0.f, 0.f, 0.f};

        #pragma unroll
        for (int k = 0; k < 4; ++k)
            #pragma unroll
            for (int m = 0; m < 8; ++m) {
                short8 a = *(const short8*)&sA[(m * 16 + c_lo) * 136 + k * 32 + c_hi * 8];
                #pragma unroll
                for (int n4 = 0; n4 < 4; ++n4)
                    acc[m][n4] = __builtin_amdgcn_mfma_f32_16x16x32_bf16(a, bfr[n4][k], acc[m][n4], 0, 0, 0);
            }

        // epilogue: +b1, gelu, LDS accumulate per hub (rows >= rlim masked)
        int rlim = n - t * 128;
        #pragma unroll
        for (int m = 0; m < 8; ++m) {
            int rbase = m * 16 + c_hi * 4;
            #pragma unroll
            for (int n4 = 0; n4 < 4; ++n4) {
                int col = w * 64 + n4 * 16 + c_lo;
                float4v a4 = acc[m][n4];
                #pragma unroll
                for (int r = 0; r < 4; ++r) {
                    int row = rbase + r;
                    if (row < rlim) {
                        float gv = gelu_f(a4[r] + bcol[n4]);
                        atomicAdd(&accS[sHub[row] * 260 + col], gv);
                    }
                }
            }
        }
        __syncthreads();
    }

    __syncthreads();   // covers nt==0 path (zero-init -> flush)

    // one flush per block: plain stores into chunk partial (or atomic fallback)
    for (int i = tid; i < NH * DIM2; i += 256) {
        int hub = i >> 8, col = i & 255;
        float v = accS[hub * 260 + col];
        size_t o = ((size_t)g * NH + hub) * DIM2 + col;
        if (atomic_mode) atomicAdd(&outbuf[o], v);
        else outbuf[(size_t)cchunk * BH * DIM2 + o] = v;
    }
}

// ---------- hub_features = (hubsum@W2 + cnt*b2) / max(cnt,1) ----------
__global__ void hubfeat_kernel(const float* __restrict__ part, int nchunk,
                               const int* __restrict__ cnt,
                               const float* __restrict__ W2, const float* __restrict__ b2,
                               float* __restrict__ out) {
    __shared__ float sSum[16 * 256];
    int tid = threadIdx.x;
    int d   = tid & 127;
    int hh  = tid >> 7;

    for (int i = tid; i < 16 * 256; i += 256) {
        int hr = i >> 8, k = i & 255;
        size_t o = (size_t)(blockIdx.x * 16 + hr) * DIM2 + k;
        float v = part[o];
        if (nchunk == 2) v += part[(size_t)BH * DIM2 + o];
        sSum[i] = v;
    }
    __syncthreads();

    int h0 = hh * 8;
    float acc[8] = {0.f, 0.f, 0.f, 0.f, 0.f, 0.f, 0.f, 0.f};
    for (int k = 0; k < DIM2; ++k) {
        float wv = W2[k * DIM + d];
        #pragma unroll
        for (int j = 0; j < 8; ++j) acc[j] += sSum[(h0 + j) * 256 + k] * wv;
    }
    float b2d = b2[d];
    #pragma unroll
    for (int j = 0; j < 8; ++j) {
        int h = blockIdx.x * 16 + h0 + j;
        float c = (float)cnt[h];
        out[OUT_HF + h * DIM + d] = (acc[j] + c * b2d) / fmaxf(c, 1.0f);
    }
}

// ---------- per-graph KNN (K=4 incl. self) ----------
__global__ void knn_kernel(const float* __restrict__ hf, int* __restrict__ knn) {
    __shared__ float s[64 * 129];
    __shared__ float d2[64 * 64];
    int g = blockIdx.x, tid = threadIdx.x;

    for (int i = tid; i < 64 * 128; i += 256) {
        int r = i >> 7, c = i & 127;
        s[r * 129 + c] = hf[OUT_HF + (g * 64 + r) * DIM + c];
    }
    __syncthreads();

    for (int p = tid; p < 4096; p += 256) {
        int i = p >> 6, j = p & 63;
        float a = 0.f;
        for (int k = 0; k < 128; ++k) {
            float dd = s[i * 129 + k] - s[j * 129 + k];
            a += dd * dd;
        }
        d2[p] = a;
    }
    __syncthreads();

    if (tid < 64) {
        float bv0 = 1e30f, bv1 = 1e30f, bv2 = 1e30f, bv3 = 1e30f;
        int   bi0 = 0,     bi1 = 0,     bi2 = 0,     bi3 = 0;
        for (int j = 0; j < 64; ++j) {
            float v = d2[tid * 64 + j];
            if (v < bv0)      { bv3=bv2; bi3=bi2; bv2=bv1; bi2=bi1; bv1=bv0; bi1=bi0; bv0=v; bi0=j; }
            else if (v < bv1) { bv3=bv2; bi3=bi2; bv2=bv1; bi2=bi1; bv1=v;   bi1=j; }
            else if (v < bv2) { bv3=bv2; bi3=bi2; bv2=v;   bi2=j; }
            else if (v < bv3) { bv3=v;   bi3=j; }
        }
        int base = (g * 64 + tid) * 4;
        knn[base + 0] = bi0; knn[base + 1] = bi1; knn[base + 2] = bi2; knn[base + 3] = bi3;
    }
}

// ---------- edges ----------
__global__ void edges_kernel(const int* __restrict__ hubidx, const int* __restrict__ batchidx,
                             const int* __restrict__ knn, float* __restrict__ out) {
    int i = blockIdx.x * 256 + threadIdx.x;
    if (i < N_SPOKES) {
        int b = batchidx[i], h = hubidx[i];
        const int4* kp = (const int4*)&knn[(b * NH + h) * 4];
        int4 kn = *kp;
        float fi = (float)i;
        float4v o0 = { fi, fi, fi, fi };
        ((float4v*)(out + OUT_E0))[i] = o0;
        float base = (float)(b * NH);
        float4v o1 = { kn.x + base, kn.y + base, kn.z + base, kn.w + base };
        ((float4v*)(out + OUT_E1))[i] = o1;
    }
}

extern "C" void kernel_launch(void* const* d_in, const int* in_sizes, int n_in,
                              void* d_out, int out_size, void* d_ws, size_t ws_size,
                              hipStream_t stream) {
    const float* x        = (const float*)d_in[0];
    const int*   hubidx   = (const int*)d_in[1];
    const int*   batchidx = (const int*)d_in[2];
    const float* W1       = (const float*)d_in[3];
    const float* b1       = (const float*)d_in[4];
    const float* W2       = (const float*)d_in[5];
    const float* b2       = (const float*)d_in[6];
    float* out = (float*)d_out;
    char*  ws  = (char*)d_ws;

    // partial mode layout (needs ~17.0 MB); atomic fallback fits in ~8.6 MB
    const size_t need_partial = 17007108;
    int atomic_mode = (ws_size < need_partial) ? 1 : 0;

    float*          part;   // partial[2][BH][256] or hubsum[BH][256]
    int*            cnt;
    unsigned short* w1t;
    int*            knn;
    int*            goff;
    if (!atomic_mode) {
        part = (float*)ws;                          // 16777216 B
        cnt  = (int*)(ws + 16777216);               // 32768 B
        w1t  = (unsigned short*)(ws + 16809984);    // 65536 B
        knn  = (int*)(ws + 16875520);               // 131072 B
        goff = (int*)(ws + 17006592);               // 516 B
    } else {
        part = (float*)ws;                          // 8388608 B (hubsum)
        cnt  = (int*)(ws + 8388608);
        w1t  = (unsigned short*)(ws + 8421376);
        knn  = (int*)(ws + 8486912);
        goff = (int*)(ws + 8617984);
    }

    (void)hipMemsetAsync(cnt, 0, 32768, stream);
    if (atomic_mode) (void)hipMemsetAsync(part, 0, 8388608, stream);

    prep_w1t    <<<128,  256, 0, stream>>>(W1, w1t);
    goff_kernel <<<2048, 256, 0, stream>>>(batchidx, goff);
    count_kernel<<<2048, 256, 0, stream>>>(hubidx, batchidx, cnt);
    ffn_fused   <<<256,  256, 0, stream>>>(x, hubidx, goff, w1t, b1, part, atomic_mode);
    hubfeat_kernel<<<512, 256, 0, stream>>>(part, atomic_mode ? 1 : 2, cnt, W2, b2, out);
    knn_kernel  <<<NB,   256, 0, stream>>>(out, knn);
    edges_kernel<<<2048, 256, 0, stream>>>(hubidx, batchidx, knn, out);
}

// Round 5
// 550.905 us; speedup vs baseline: 2.1039x; 2.1039x over previous
//
#include <hip/hip_runtime.h>
#include <hip/hip_bf16.h>

#define N_SPOKES 524288
#define DIM      128
#define DIM2     256
#define NB       128
#define NH       64
#define BH       8192   // NB*NH

// d_out layout (all float32): [0,1048576) hub_features [8192][128]
//                             [1048576, +2097152) spokes_idx row
//                             [3145728, +2097152) hub ids row
#define OUT_HF   0
#define OUT_E0   1048576
#define OUT_E1   3145728

typedef __attribute__((ext_vector_type(8))) short  short8;
typedef __attribute__((ext_vector_type(4))) float  float4v;
typedef __attribute__((ext_vector_type(4))) unsigned short ushort4v;

__device__ inline unsigned short f2bf(float f) {
    __hip_bfloat16 h = __float2bfloat16(f);
    return *reinterpret_cast<unsigned short*>(&h);
}

// tanh-approx GELU via sigmoid identity
__device__ inline float gelu_f(float v) {
    float s = v * (1.0f + 0.044715f * v * v);
    float e = __builtin_exp2f(-2.302118131f * s);
    return v * __builtin_amdgcn_rcpf(1.0f + e);
}

// ---------- setup: goff + count + W1^T bf16 prep, one kernel ----------
__global__ void setup_kernel(const int* __restrict__ batchidx, const int* __restrict__ hubidx,
                             const float* __restrict__ W1,
                             unsigned short* __restrict__ w1t,
                             int* __restrict__ goff, int* __restrict__ cnt) {
    int b = blockIdx.x, tid = threadIdx.x;
    if (b < 2048) {
        int i = b * 256 + tid;
        if (i < N_SPOKES) {
            int bi = batchidx[i];
            int bp = (i == 0) ? -1 : batchidx[i - 1];
            for (int g = bp + 1; g <= bi; ++g) goff[g] = i;
            if (i == N_SPOKES - 1)
                for (int g = bi + 1; g <= NB; ++g) goff[g] = N_SPOKES;
            atomicAdd(&cnt[bi * NH + hubidx[i]], 1);
        }
    } else {
        int idx = (b - 2048) * 256 + tid;   // 128 blocks -> 32768
        if (idx < DIM * DIM2) {
            int n = idx >> 7, k = idx & 127;
            w1t[idx] = f2bf(W1[k * DIM2 + n]);
        }
    }
}

// ---------- fused FFN + scatter-as-GEMM ----------
// 256 blocks = 128 graphs x 2 chunks, 1 block/CU (LDS ~105 KB).
// Per tile (128 spokes): main GEMM U=gelu(x@W1+b1) [128x256] via mfma 16x16x32;
// U round-trips LDS as bf16 U^T[col][row] (wave-private cols -> no barrier);
// hub GEMM hacc[64x256] += onehot(S)^T @ U with register-built one-hot A.
// hacc lives in fp32 C-registers across all tiles; one plain-store flush.
__launch_bounds__(256, 1)
__global__ void ffn_fused(const float* __restrict__ x,
                          const int* __restrict__ hubidx,
                          const int* __restrict__ goff,
                          const unsigned short* __restrict__ w1t,
                          const float* __restrict__ b1,
                          float* __restrict__ outbuf,
                          int atomic_mode) {
    __shared__ unsigned short sA[128 * 136];   // bf16 A tile (x), row stride 136
    __shared__ unsigned short sU[256 * 136];   // bf16 U^T [col][row], stride 136
    __shared__ int sHub[128];

    const int tid  = threadIdx.x;
    const int lane = tid & 63;
    const int w    = tid >> 6;
    const int c_lo = lane & 15;
    const int c_hi = lane >> 4;
    const int g      = blockIdx.x >> 1;
    const int cchunk = blockIdx.x & 1;

    const int s = goff[g], e = goff[g + 1];
    const int len = e - s;
    const int cs  = (len + 1) >> 1;
    const int ms  = s + cchunk * cs;
    int me = ms + cs; if (me > e) me = e;
    const int n  = me - ms;
    const int nt = (n + 127) >> 7;

    // W1^T fragments + bias (wave-private cols, L1-resident)
    short8 bfr[4][4];
    #pragma unroll
    for (int n4 = 0; n4 < 4; ++n4)
        #pragma unroll
        for (int k = 0; k < 4; ++k) {
            int col = w * 64 + n4 * 16 + c_lo;
            bfr[n4][k] = *(const short8*)(w1t + col * DIM + k * 32 + c_hi * 8);
        }
    float bcol[4];
    #pragma unroll
    for (int n4 = 0; n4 < 4; ++n4) bcol[n4] = b1[w * 64 + n4 * 16 + c_lo];

    // hub accumulator [64 hubs x 64 wave-cols] in fp32 C-regs
    float4v hacc[4][4];
    #pragma unroll
    for (int mt = 0; mt < 4; ++mt)
        #pragma unroll
        for (int n4 = 0; n4 < 4; ++n4) hacc[mt][n4] = (float4v){0.f, 0.f, 0.f, 0.f};

    const float4v* x4 = (const float4v*)x;

    float4v pf[16];
    if (nt > 0) {
        #pragma unroll
        for (int it = 0; it < 16; ++it) {
            int f = it * 256 + tid;
            int r = f >> 5;
            int rr = r < n ? r : n - 1;
            pf[it] = x4[(size_t)(ms + rr) * 32 + (f & 31)];
        }
    }

    for (int t = 0; t < nt; ++t) {
        // stage prefetched x tile -> sA (f32->bf16)
        #pragma unroll
        for (int it = 0; it < 16; ++it) {
            int f = it * 256 + tid;
            int row = f >> 5, c4 = f & 31;
            float4v v = pf[it];
            ushort4v u = { f2bf(v.x), f2bf(v.y), f2bf(v.z), f2bf(v.w) };
            *(ushort4v*)&sA[row * 136 + c4 * 4] = u;
        }
        if (tid < 128) {
            int r = t * 128 + tid;
            sHub[tid] = (r < n) ? hubidx[ms + r] : -1;   // -1 masks padded rows
        }
        __syncthreads();

        // prefetch next tile (fires during compute)
        if (t + 1 < nt) {
            #pragma unroll
            for (int it = 0; it < 16; ++it) {
                int f = it * 256 + tid;
                int r = (t + 1) * 128 + (f >> 5);
                int rr = r < n ? r : n - 1;
                pf[it] = x4[(size_t)(ms + rr) * 32 + (f & 31)];
            }
        }

        // main GEMM: U = x @ W1
        float4v acc[8][4];
        #pragma unroll
        for (int m = 0; m < 8; ++m)
            #pragma unroll
            for (int n4 = 0; n4 < 4; ++n4) acc[m][n4] = (float4v){0.f, 0.f, 0.f, 0.f};

        #pragma unroll
        for (int k = 0; k < 4; ++k)
            #pragma unroll
            for (int m = 0; m < 8; ++m) {
                short8 a = *(const short8*)&sA[(m * 16 + c_lo) * 136 + k * 32 + c_hi * 8];
                #pragma unroll
                for (int n4 = 0; n4 < 4; ++n4)
                    acc[m][n4] = __builtin_amdgcn_mfma_f32_16x16x32_bf16(a, bfr[n4][k], acc[m][n4], 0, 0, 0);
            }

        // epilogue: +b1, gelu, write bf16 U^T into wave-private sU cols
        #pragma unroll
        for (int m = 0; m < 8; ++m) {
            int rbase = m * 16 + c_hi * 4;
            #pragma unroll
            for (int n4 = 0; n4 < 4; ++n4) {
                int col = w * 64 + n4 * 16 + c_lo;
                float4v a4 = acc[m][n4];
                ushort4v u;
                u.x = f2bf(gelu_f(a4.x + bcol[n4]));
                u.y = f2bf(gelu_f(a4.y + bcol[n4]));
                u.z = f2bf(gelu_f(a4.z + bcol[n4]));
                u.w = f2bf(gelu_f(a4.w + bcol[n4]));
                *(ushort4v*)&sU[col * 136 + rbase] = u;
            }
        }

        // hub GEMM: hacc += onehot^T @ U   (same-wave sU data; compiler waits lgkmcnt)
        #pragma unroll
        for (int ks = 0; ks < 4; ++ks) {
            int4 h0v = *(const int4*)&sHub[ks * 32 + c_hi * 8];
            int4 h1v = *(const int4*)&sHub[ks * 32 + c_hi * 8 + 4];
            short8 aS[4];
            #pragma unroll
            for (int mt = 0; mt < 4; ++mt) {
                int hb = mt * 16 + c_lo;
                short8 a;
                a[0] = (h0v.x == hb) ? (short)0x3F80 : (short)0;
                a[1] = (h0v.y == hb) ? (short)0x3F80 : (short)0;
                a[2] = (h0v.z == hb) ? (short)0x3F80 : (short)0;
                a[3] = (h0v.w == hb) ? (short)0x3F80 : (short)0;
                a[4] = (h1v.x == hb) ? (short)0x3F80 : (short)0;
                a[5] = (h1v.y == hb) ? (short)0x3F80 : (short)0;
                a[6] = (h1v.z == hb) ? (short)0x3F80 : (short)0;
                a[7] = (h1v.w == hb) ? (short)0x3F80 : (short)0;
                aS[mt] = a;
            }
            short8 bU[4];
            #pragma unroll
            for (int n4 = 0; n4 < 4; ++n4) {
                int col = w * 64 + n4 * 16 + c_lo;
                bU[n4] = *(const short8*)&sU[col * 136 + ks * 32 + c_hi * 8];
            }
            #pragma unroll
            for (int mt = 0; mt < 4; ++mt)
                #pragma unroll
                for (int n4 = 0; n4 < 4; ++n4)
                    hacc[mt][n4] = __builtin_amdgcn_mfma_f32_16x16x32_bf16(aS[mt], bU[n4], hacc[mt][n4], 0, 0, 0);
        }
        __syncthreads();
    }

    // flush: hub = mt*16 + c_hi*4 + reg, col = w*64 + n4*16 + c_lo
    #pragma unroll
    for (int mt = 0; mt < 4; ++mt)
        #pragma unroll
        for (int n4 = 0; n4 < 4; ++n4) {
            float4v v = hacc[mt][n4];
            int col = w * 64 + n4 * 16 + c_lo;
            #pragma unroll
            for (int reg = 0; reg < 4; ++reg) {
                int hub = mt * 16 + c_hi * 4 + reg;
                size_t o = ((size_t)g * NH + hub) * DIM2 + col;
                if (atomic_mode) atomicAdd(&outbuf[o], v[reg]);
                else outbuf[(size_t)cchunk * BH * DIM2 + o] = v[reg];
            }
        }
}

// ---------- hub_features = (hubsum@W2 + cnt*b2) / max(cnt,1) ----------
__global__ void hubfeat_kernel(const float* __restrict__ part, int nchunk,
                               const int* __restrict__ cnt,
                               const float* __restrict__ W2, const float* __restrict__ b2,
                               float* __restrict__ out) {
    __shared__ float sSum[16 * 256];
    int tid = threadIdx.x;
    int d   = tid & 127;
    int hh  = tid >> 7;

    for (int i = tid; i < 16 * 256; i += 256) {
        size_t o = (size_t)(blockIdx.x * 16) * DIM2 + i;
        float v = part[o];
        if (nchunk == 2) v += part[(size_t)BH * DIM2 + o];
        sSum[i] = v;
    }
    __syncthreads();

    int h0 = hh * 8;
    float acc[8] = {0.f, 0.f, 0.f, 0.f, 0.f, 0.f, 0.f, 0.f};
    for (int k4 = 0; k4 < 64; ++k4) {
        float w0 = W2[(k4 * 4 + 0) * DIM + d];
        float w1 = W2[(k4 * 4 + 1) * DIM + d];
        float w2 = W2[(k4 * 4 + 2) * DIM + d];
        float w3 = W2[(k4 * 4 + 3) * DIM + d];
        #pragma unroll
        for (int j = 0; j < 8; ++j) {
            float4v sv = *(const float4v*)&sSum[(h0 + j) * 256 + k4 * 4];
            acc[j] += sv.x * w0 + sv.y * w1 + sv.z * w2 + sv.w * w3;
        }
    }
    float b2d = b2[d];
    #pragma unroll
    for (int j = 0; j < 8; ++j) {
        int h = blockIdx.x * 16 + h0 + j;
        float c = (float)cnt[h];
        out[OUT_HF + h * DIM + d] = (acc[j] + c * b2d) / fmaxf(c, 1.0f);
    }
}

// ---------- per-graph KNN + edge emission (merged) ----------
__global__ void knn_edges(const float* __restrict__ hf, const int* __restrict__ goff,
                          const int* __restrict__ hubidx, float* __restrict__ out) {
    __shared__ float s[64 * 129];
    __shared__ float d2[64 * 64];
    __shared__ int sK[64 * 4];
    int g = blockIdx.x, tid = threadIdx.x;

    for (int i = tid; i < 64 * 128; i += 256) {
        int r = i >> 7, c = i & 127;
        s[r * 129 + c] = hf[OUT_HF + (g * 64 + r) * DIM + c];
    }
    __syncthreads();

    for (int p = tid; p < 4096; p += 256) {
        int i = p >> 6, j = p & 63;
        float a = 0.f;
        for (int k = 0; k < 128; ++k) {
            float dd = s[i * 129 + k] - s[j * 129 + k];
            a += dd * dd;
        }
        d2[p] = a;
    }
    __syncthreads();

    if (tid < 64) {
        float bv0 = 1e30f, bv1 = 1e30f, bv2 = 1e30f, bv3 = 1e30f;
        int   bi0 = 0,     bi1 = 0,     bi2 = 0,     bi3 = 0;
        for (int j = 0; j < 64; ++j) {
            float v = d2[tid * 64 + j];
            if (v < bv0)      { bv3=bv2; bi3=bi2; bv2=bv1; bi2=bi1; bv1=bv0; bi1=bi0; bv0=v; bi0=j; }
            else if (v < bv1) { bv3=bv2; bi3=bi2; bv2=bv1; bi2=bi1; bv1=v;   bi1=j; }
            else if (v < bv2) { bv3=bv2; bi3=bi2; bv2=v;   bi2=j; }
            else if (v < bv3) { bv3=v;   bi3=j; }
        }
        sK[tid * 4 + 0] = bi0; sK[tid * 4 + 1] = bi1;
        sK[tid * 4 + 2] = bi2; sK[tid * 4 + 3] = bi3;
    }
    __syncthreads();

    int sgs = goff[g], sge = goff[g + 1];
    float gbase = (float)(g * NH);
    for (int i = sgs + tid; i < sge; i += 256) {
        int h = hubidx[i];
        int4 kn = *(const int4*)&sK[h * 4];
        float fi = (float)i;
        float4v o0 = { fi, fi, fi, fi };
        ((float4v*)(out + OUT_E0))[i] = o0;
        float4v o1 = { kn.x + gbase, kn.y + gbase, kn.z + gbase, kn.w + gbase };
        ((float4v*)(out + OUT_E1))[i] = o1;
    }
}

extern "C" void kernel_launch(void* const* d_in, const int* in_sizes, int n_in,
                              void* d_out, int out_size, void* d_ws, size_t ws_size,
                              hipStream_t stream) {
    const float* x        = (const float*)d_in[0];
    const int*   hubidx   = (const int*)d_in[1];
    const int*   batchidx = (const int*)d_in[2];
    const float* W1       = (const float*)d_in[3];
    const float* b1       = (const float*)d_in[4];
    const float* W2       = (const float*)d_in[5];
    const float* b2       = (const float*)d_in[6];
    float* out = (float*)d_out;
    char*  ws  = (char*)d_ws;

    const size_t need_partial = 16879616;   // part 16MB + cnt + w1t + goff
    int atomic_mode = (ws_size < need_partial) ? 1 : 0;

    float*          part;
    int*            cnt;
    unsigned short* w1t;
    int*            goff;
    if (!atomic_mode) {
        part = (float*)ws;                          // 16777216 B
        cnt  = (int*)(ws + 16777216);               // 32768 B
        w1t  = (unsigned short*)(ws + 16809984);    // 65536 B
        goff = (int*)(ws + 16875520);               // 2048 B
    } else {
        part = (float*)ws;                          // 8388608 B
        cnt  = (int*)(ws + 8388608);
        w1t  = (unsigned short*)(ws + 8421376);
        goff = (int*)(ws + 8486912);
    }

    (void)hipMemsetAsync(cnt, 0, 32768, stream);
    if (atomic_mode) (void)hipMemsetAsync(part, 0, 8388608, stream);

    setup_kernel<<<2176, 256, 0, stream>>>(batchidx, hubidx, W1, w1t, goff, cnt);
    ffn_fused   <<<256,  256, 0, stream>>>(x, hubidx, goff, w1t, b1, part, atomic_mode);
    hubfeat_kernel<<<512, 256, 0, stream>>>(part, atomic_mode ? 1 : 2, cnt, W2, b2, out);
    knn_edges   <<<NB,   256, 0, stream>>>(out, goff, hubidx, out);
}